// Round 11
// baseline (240.645 us; speedup 1.0000x reference)
//
#include <hip/hip_runtime.h>
#include <hip/hip_bf16.h>
#include <math.h>

// ---------- types / helpers ----------
typedef __attribute__((ext_vector_type(8))) short short8;    // 8 bf16
typedef __attribute__((ext_vector_type(4))) float f32x4;
typedef __attribute__((ext_vector_type(16))) float f32x16;
typedef __attribute__((ext_vector_type(4))) unsigned u32x4;

#define MFMA_BF16(a, b, c) __builtin_amdgcn_mfma_f32_16x16x32_bf16(a, b, c, 0, 0, 0)
#define MFMA32_BF16(a, b, c) __builtin_amdgcn_mfma_f32_32x32x16_bf16(a, b, c, 0, 0, 0)
#define BAR() __builtin_amdgcn_s_barrier()
#define SCHEDB() __builtin_amdgcn_sched_barrier(0)
// rule #18: lgkmcnt(0) + sched_barrier so MFMA can't hoist past the wait
#define LGKM0()                                             \
  do {                                                      \
    asm volatile("s_waitcnt lgkmcnt(0)" ::: "memory");      \
    __builtin_amdgcn_sched_barrier(0);                      \
  } while (0)

// async global->LDS, 16B per lane; LDS dest = wave-uniform base + lane*16
#define GLD_LDS16(g, l)                                              \
  __builtin_amdgcn_global_load_lds(                                  \
      (const __attribute__((address_space(1))) void*)(g),            \
      (__attribute__((address_space(3))) void*)(l), 16, 0, 0)

// counted vmcnt wait (T4): keep N VMEM ops in flight across the barrier
template <int N>
__device__ __forceinline__ void waitcnt_vm() {
  if constexpr (N == 0) asm volatile("s_waitcnt vmcnt(0)" ::: "memory");
  else if constexpr (N == 2) asm volatile("s_waitcnt vmcnt(2)" ::: "memory");
  else if constexpr (N == 4) asm volatile("s_waitcnt vmcnt(4)" ::: "memory");
  else if constexpr (N == 6) asm volatile("s_waitcnt vmcnt(6)" ::: "memory");
  else if constexpr (N == 8) asm volatile("s_waitcnt vmcnt(8)" ::: "memory");
}

// packed 2xf32 -> 2xbf16 (RNE); no builtin on gfx950 (m240) -> inline asm
__device__ __forceinline__ unsigned cvt_pk_bf16(float lo, float hi) {
  unsigned r;
  asm("v_cvt_pk_bf16_f32 %0, %1, %2" : "=v"(r) : "v"(lo), "v"(hi));
  return r;
}
#define PSWAP(a, b) asm volatile("v_permlane32_swap_b32 %0, %1" : "+v"(a), "+v"(b))

__device__ __forceinline__ unsigned short f2bf(float f) {
  union { float f; unsigned u; } v; v.f = f;
  unsigned r = v.u + 0x7FFFu + ((v.u >> 16) & 1u);   // RNE
  return (unsigned short)(r >> 16);
}
__device__ __forceinline__ float bf2f(unsigned short u) {
  union { unsigned u; float f; } v; v.u = ((unsigned)u) << 16;
  return v.f;
}

// ---------- weight repack: [R][C] f32 -> [C][R] bf16 (batched) ----------
__global__ __launch_bounds__(256) void transpose_cast(
    const float* __restrict__ in, unsigned short* __restrict__ out,
    int R, int C, size_t in_bs, size_t out_bs) {
  __shared__ float t[32][33];
  const float* inp = in + blockIdx.z * in_bs;
  unsigned short* outp = out + blockIdx.z * out_bs;
  const int c0 = blockIdx.x * 32, r0 = blockIdx.y * 32;
  const int tx = threadIdx.x, ty = threadIdx.y;
#pragma unroll
  for (int i = 0; i < 32; i += 8)
    t[ty + i][tx] = inp[(size_t)(r0 + ty + i) * C + c0 + tx];
  __syncthreads();
#pragma unroll
  for (int i = 0; i < 32; i += 8)
    outp[(size_t)(c0 + ty + i) * R + r0 + tx] = f2bf(t[tx][ty + i]);
}

__global__ void concat_bias(const float* __restrict__ bq, const float* __restrict__ bk,
                            const float* __restrict__ bv, float* __restrict__ bcat) {
  int i = blockIdx.x * 256 + threadIdx.x;
  if (i < 1024) bcat[i] = bq[i];
  else if (i < 2048) bcat[i] = bk[i - 1024];
  else if (i < 3072) bcat[i] = bv[i - 2048];
}

// ---------- V transpose: qkv V-cols [s][d] -> vt[b*16+h][d=64][s=2048] bf16 ----
__global__ __launch_bounds__(512) void vtrans(
    const unsigned short* __restrict__ qkv, unsigned short* __restrict__ vt) {
  __shared__ unsigned short t[64][65];
  const int bh = blockIdx.y;            // b*16+h
  const int s0 = blockIdx.x * 64;
  const int tx = threadIdx.x;           // 0..63 (d on read, s on write)
  const int ty = threadIdx.y;           // 0..7
  const unsigned short* in =
      qkv + (size_t)(bh >> 4) * 2048 * 3072 + 2048 + (bh & 15) * 64;
#pragma unroll
  for (int i = 0; i < 8; ++i)
    t[ty * 8 + i][tx] = in[(size_t)(s0 + ty * 8 + i) * 3072 + tx];
  __syncthreads();
  unsigned short* o = vt + (size_t)bh * 64 * 2048 + s0;
#pragma unroll
  for (int i = 0; i < 8; ++i)
    o[(size_t)(ty * 8 + i) * 2048 + tx] = t[tx][ty * 8 + i];
}

// ---------- LayerNorm: row of 1024 f32 -> bf16 ----------
__global__ __launch_bounds__(256) void ln_kernel(
    const float* __restrict__ x, const float* __restrict__ g,
    const float* __restrict__ bb, unsigned short* __restrict__ out) {
  const int row = blockIdx.x, tid = threadIdx.x;
  const float4 v = ((const float4*)(x + (size_t)row * 1024))[tid];
  float s = v.x + v.y + v.z + v.w;
  float ss = v.x * v.x + v.y * v.y + v.z * v.z + v.w * v.w;
#pragma unroll
  for (int k = 1; k < 64; k <<= 1) {
    s += __shfl_xor(s, k, 64);
    ss += __shfl_xor(ss, k, 64);
  }
  __shared__ float red[8];
  const int wid = tid >> 6;
  if ((tid & 63) == 0) { red[wid] = s; red[wid + 4] = ss; }
  __syncthreads();
  s = red[0] + red[1] + red[2] + red[3];
  ss = red[4] + red[5] + red[6] + red[7];
  const float mu = s * (1.0f / 1024.0f);
  const float var = ss * (1.0f / 1024.0f) - mu * mu;
  const float rs = rsqrtf(var + 1e-5f);
  const float4 gv = ((const float4*)g)[tid];
  const float4 bv = ((const float4*)bb)[tid];
  ushort4 o;
  o.x = f2bf((v.x - mu) * rs * gv.x + bv.x);
  o.y = f2bf((v.y - mu) * rs * gv.y + bv.y);
  o.z = f2bf((v.z - mu) * rs * gv.z + bv.z);
  o.w = f2bf((v.w - mu) * rs * gv.w + bv.w);
  ((ushort4*)(out + (size_t)row * 1024))[tid] = o;
}

// ---------- 256^2 8-phase GEMM (m201-faithful): C = A[M,K] x Bt[N,K]^T --------
// 512 thr = 8 waves (2M x 4N), per-wave out 128x64, BK=64, dbuf 128KB LDS.
// Phase = {ds-reads; stage; [vmcnt@p3/p7 tail]; SCHEDB; BAR; LGKM0; 16 MFMA; BAR}
// -- reads issued BEFORE the barrier so latency hides under barrier-wait.
// vmcnt(2) at p3/p7 tails: only A0(t_next)'s 2 DMAs newer than the buffer
// being opened -> buffer fully landed after that barrier (ledger-verified).
// EPI 0: +bias->bf16 | 2: +bias+GELU->bf16 | 3: raw bf16 partial -> pz
template <int QM, int QN>
__device__ __forceinline__ void mfq(f32x4 (&acc)[8][4], short8 (&af)[4][2],
                                    short8 (&bf)[2][2]) {
  __builtin_amdgcn_s_setprio(1);
#pragma unroll
  for (int i = 0; i < 4; ++i)
#pragma unroll
    for (int nf = 0; nf < 2; ++nf) {
      acc[QM * 4 + i][QN * 2 + nf] =
          MFMA_BF16(af[i][0], bf[nf][0], acc[QM * 4 + i][QN * 2 + nf]);
      acc[QM * 4 + i][QN * 2 + nf] =
          MFMA_BF16(af[i][1], bf[nf][1], acc[QM * 4 + i][QN * 2 + nf]);
    }
  __builtin_amdgcn_s_setprio(0);
}

template <int EPI>
__global__ __launch_bounds__(512, 2) void gemm256(
    const unsigned short* __restrict__ A, const unsigned short* __restrict__ Bt,
    const float* __restrict__ bias, void* __restrict__ Cout,
    int M, int N, int K,
    unsigned short* __restrict__ p0p, unsigned short* __restrict__ p1p,
    unsigned short* __restrict__ p2p, unsigned short* __restrict__ p3p) {
  extern __shared__ unsigned short L[];   // [buf][op][half][8192] el = 128KB
  const int tid = threadIdx.x;
  const int wv = tid >> 6, lane = tid & 63;
  const int li = lane & 15, gi = lane >> 4;
  const int wm = wv >> 2, wn = wv & 3;    // 2 x 4 wave grid
  // T1: bijective XCD swizzle (nwg % 8 == 0 for all our grids)
  const int gx = gridDim.x;
  const int flat = blockIdx.y * gx + blockIdx.x;
  const int swz = (flat & 7) * ((gx * gridDim.y) >> 3) + (flat >> 3);
  const int bm = swz / gx, bn = swz - bm * gx;
  const size_t Ksz = (size_t)K;
  const int k0 = (int)(blockIdx.z << 10);   // 1024 K per z-slice, always

  auto lds = [&](int buf, int op, int half) -> unsigned short* {
    return L + (size_t)(((buf * 2 + op) * 2 + half)) * 8192;
  };

  // staging: issue covers rows (tid>>3) + c*64; seg pre-swizzled (both-sides, #21)
  const int sr8 = tid >> 3;
  const int segG = (tid & 7) ^ (sr8 & 7);
  const unsigned short* Ag = A + (size_t)(bm * 256 + sr8) * Ksz + segG * 8 + k0;
  const unsigned short* Bg = Bt + (size_t)(bn * 256 + sr8) * Ksz + segG * 8 + k0;
  const int wbase = wv * 512;

  auto stg = [&](int buf, int op, int half, int tile) {
    const unsigned short* g =
        (op ? Bg : Ag) + (size_t)(half * 128) * Ksz + (tile & 15) * 64;
    unsigned short* d = lds(buf, op, half);
    GLD_LDS16(g, d + wbase);
    GLD_LDS16(g + (size_t)64 * Ksz, d + 4096 + wbase);
  };

  f32x4 acc[8][4];
#pragma unroll
  for (int m = 0; m < 8; ++m)
#pragma unroll
    for (int n = 0; n < 4; ++n) acc[m][n] = (f32x4)0.0f;

  short8 af[4][2], b0[2][2], b1[2][2];
  auto ldA = [&](int buf, int qm) {
    const unsigned short* p = lds(buf, 0, wm);
#pragma unroll
    for (int i = 0; i < 4; ++i) {
      const int r = qm * 64 + i * 16 + li;
#pragma unroll
      for (int kk = 0; kk < 2; ++kk)
        af[i][kk] = *(const short8*)(p + r * 64 + (((kk * 4 + gi) ^ (r & 7)) * 8));
    }
  };
  auto ldB = [&](short8 (&bf)[2][2], int buf, int qn) {
    const unsigned short* p = lds(buf, 1, wn >> 1);
#pragma unroll
    for (int nf = 0; nf < 2; ++nf) {
      const int r = (wn & 1) * 64 + qn * 32 + nf * 16 + li;
#pragma unroll
      for (int kk = 0; kk < 2; ++kk)
        bf[nf][kk] = *(const short8*)(p + r * 64 + (((kk * 4 + gi) ^ (r & 7)) * 8));
    }
  };

  // prologue: T0 all halves + A0(T1); vmcnt(2) leaves A0(T1) in flight
  stg(0, 0, 0, 0); stg(0, 0, 1, 0); stg(0, 1, 0, 0); stg(0, 1, 1, 0);
  stg(1, 0, 0, 1);
  waitcnt_vm<2>();
  BAR();

  for (int j = 0; j < 8; ++j) {
    const int t1 = 2 * j + 1, t2 = 2 * j + 2, t3 = 2 * j + 3;
    // p0 (buf0, q00): reads safe (prev barrier covered buf0 tile 2j)
    ldA(0, 0); ldB(b0, 0, 0);
    stg(1, 0, 1, t1); stg(1, 1, 0, t1);
    SCHEDB();
    BAR();
    LGKM0();
    mfq<0, 0>(acc, af, b0);
    BAR();
    // p1 (q01)
    ldB(b1, 0, 1);
    stg(1, 1, 1, t1);
    SCHEDB();
    BAR();
    LGKM0();
    mfq<0, 1>(acc, af, b1);
    BAR();
    // p2 (q10)
    ldA(0, 1);
    SCHEDB();
    BAR();
    LGKM0();
    mfq<1, 0>(acc, af, b0);
    BAR();
    // p3 (q11): no reads; stage A0(t2); vmcnt(2) -> buf1 t1 landed after BAR
    stg(0, 0, 0, t2);
    waitcnt_vm<2>();
    SCHEDB();
    BAR();
    mfq<1, 1>(acc, af, b1);
    BAR();
    // p4 (buf1, q00)
    ldA(1, 0); ldB(b0, 1, 0);
    stg(0, 0, 1, t2); stg(0, 1, 0, t2);
    SCHEDB();
    BAR();
    LGKM0();
    mfq<0, 0>(acc, af, b0);
    BAR();
    // p5 (q01)
    ldB(b1, 1, 1);
    stg(0, 1, 1, t2);
    SCHEDB();
    BAR();
    LGKM0();
    mfq<0, 1>(acc, af, b1);
    BAR();
    // p6 (q10)
    ldA(1, 1);
    SCHEDB();
    BAR();
    LGKM0();
    mfq<1, 0>(acc, af, b0);
    BAR();
    // p7 (q11): stage A0(t3); vmcnt(2) -> buf0 t2 landed after BAR
    stg(1, 0, 0, t3);
    waitcnt_vm<2>();
    SCHEDB();
    BAR();
    mfq<1, 1>(acc, af, b1);
    BAR();
  }

  // epilogue: C row = gi*4+reg (16x16 layout), col = li
  unsigned short* Pz =
      (EPI == 3) ? ((blockIdx.z == 0) ? p0p : (blockIdx.z == 1) ? p1p
                    : (blockIdx.z == 2) ? p2p : p3p)
                 : (unsigned short*)Cout;
  const int row0 = bm * 256 + wm * 128 + gi * 4;
  const int col0 = bn * 256 + wn * 64 + li;
#pragma unroll
  for (int mf = 0; mf < 8; ++mf) {
#pragma unroll
    for (int nf = 0; nf < 4; ++nf) {
      const int col = col0 + nf * 16;
      const float bi = (EPI == 3) ? 0.0f : bias[col];
#pragma unroll
      for (int r = 0; r < 4; ++r) {
        const int row = row0 + mf * 16 + r;
        float v = acc[mf][nf][r] + bi;
        if (EPI == 2) v = 0.5f * v * (1.0f + erff(v * 0.70710678118654752f));
        Pz[(size_t)row * N + col] = f2bf(v);
      }
    }
  }
}

// ---------- FFN2 split-K combine: out += P0+P1+P2+P3 + b2 (out holds x1) ------
__global__ __launch_bounds__(256) void ffn2_combine(
    const unsigned short* __restrict__ p0, const unsigned short* __restrict__ p1,
    const unsigned short* __restrict__ p2, const unsigned short* __restrict__ p3,
    const float* __restrict__ b2, float* __restrict__ out) {
  const size_t i8 = (size_t)blockIdx.x * 256 + threadIdx.x;   // 8-elem group
  const size_t e0 = i8 * 8;
  const int col = (int)(e0 & 1023);
  const short8 a0 = *(const short8*)(p0 + e0);
  const short8 a1 = *(const short8*)(p1 + e0);
  const short8 a2 = *(const short8*)(p2 + e0);
  const short8 a3 = *(const short8*)(p3 + e0);
  float4 o0 = ((float4*)out)[i8 * 2];
  float4 o1 = ((float4*)out)[i8 * 2 + 1];
  float v[8];
#pragma unroll
  for (int j = 0; j < 8; ++j)
    v[j] = bf2f((unsigned short)a0[j]) + bf2f((unsigned short)a1[j]) +
           bf2f((unsigned short)a2[j]) + bf2f((unsigned short)a3[j]) + b2[col + j];
  o0.x += v[0]; o0.y += v[1]; o0.z += v[2]; o0.w += v[3];
  o1.x += v[4]; o1.y += v[5]; o1.z += v[6]; o1.w += v[7];
  ((float4*)out)[i8 * 2] = o0;
  ((float4*)out)[i8 * 2 + 1] = o1;
}

// ---------- 128xBN pipelined GEMM (counted vmcnt) for N=1024 ops --------------
// EPI 1: +bias +res(f32) -> f32
template <int EPI, int BN>
__global__ __launch_bounds__(256, (BN == 128) ? 2 : 3) void gemm_bt(
    const unsigned short* __restrict__ A, const unsigned short* __restrict__ Bt,
    const float* __restrict__ bias, const float* __restrict__ res,
    void* __restrict__ Cout, int M, int N, int K) {
  constexpr int NFR = BN / 32;
  constexpr int BISS = BN / 32;
  constexpr int ISS = 4 + BISS;
  __shared__ unsigned short As[2][128 * 64];
  __shared__ unsigned short Bs[2][BN * 64];
  const int tid = threadIdx.x;
  const int wid = tid >> 6, lane = tid & 63;
  const int li = lane & 15, gi = lane >> 4;
  const int bm = blockIdx.y, bn = blockIdx.x;
  const int wr = (wid >> 1) << 6;
  const int wc = (wid & 1) * (BN / 2);

  f32x4 acc[4][NFR];
#pragma unroll
  for (int m = 0; m < 4; ++m)
#pragma unroll
    for (int n = 0; n < NFR; ++n) acc[m][n] = (f32x4)0.0f;

  const size_t Ksz = (size_t)K;
  const int srow = tid >> 3;
  const int segG = (tid & 7) ^ (srow & 7);
  const unsigned short* Ab = A + (size_t)(bm * 128 + srow) * Ksz + segG * 8;
  const unsigned short* Bb = Bt + (size_t)(bn * BN + srow) * Ksz + segG * 8;

  auto stage = [&](int buf, int kt) {
#pragma unroll
    for (int c = 0; c < 4; ++c)
      GLD_LDS16(Ab + (size_t)(c * 32) * Ksz + kt, &As[buf][c * 2048 + wid * 512]);
#pragma unroll
    for (int c = 0; c < BISS; ++c)
      GLD_LDS16(Bb + (size_t)(c * 32) * Ksz + kt, &Bs[buf][c * 2048 + wid * 512]);
  };

  auto compute = [&](int ib) {
    const unsigned short* As_ = As[ib];
    const unsigned short* Bs_ = Bs[ib];
    short8 af[4][2], bf[NFR][2];
#pragma unroll
    for (int m = 0; m < 4; ++m)
#pragma unroll
      for (int kk = 0; kk < 2; ++kk) {
        const int row = wr + m * 16 + li;
        af[m][kk] = *(const short8*)(As_ + row * 64 + ((kk * 4 + gi) ^ (row & 7)) * 8);
      }
#pragma unroll
    for (int n = 0; n < NFR; ++n)
#pragma unroll
      for (int kk = 0; kk < 2; ++kk) {
        const int row = wc + n * 16 + li;
        bf[n][kk] = *(const short8*)(Bs_ + row * 64 + ((kk * 4 + gi) ^ (row & 7)) * 8);
      }
    __builtin_amdgcn_s_setprio(1);
#pragma unroll
    for (int m = 0; m < 4; ++m)
#pragma unroll
      for (int n = 0; n < NFR; ++n) {
        acc[m][n] = MFMA_BF16(af[m][0], bf[n][0], acc[m][n]);
        acc[m][n] = MFMA_BF16(af[m][1], bf[n][1], acc[m][n]);
      }
    __builtin_amdgcn_s_setprio(0);
  };

  const int KT = K >> 6;
  stage(0, 0);
  for (int i = 0; i < KT - 1; ++i) {
    stage((i + 1) & 1, (i + 1) << 6);
    waitcnt_vm<ISS>();
    __builtin_amdgcn_s_barrier();
    __builtin_amdgcn_sched_barrier(0);
    compute(i & 1);
    __builtin_amdgcn_s_barrier();
  }
  waitcnt_vm<0>();
  __builtin_amdgcn_s_barrier();
  __builtin_amdgcn_sched_barrier(0);
  compute((KT - 1) & 1);

  const int row_base = bm * 128 + wr + gi * 4;
  const int col_base = bn * BN + wc + li;
#pragma unroll
  for (int m = 0; m < 4; ++m) {
#pragma unroll
    for (int n = 0; n < NFR; ++n) {
      const int col = col_base + n * 16;
      const float bi = bias[col];
#pragma unroll
      for (int r = 0; r < 4; ++r) {
        const int row = row_base + m * 16 + r;
        float v = acc[m][n][r] + bi;
        if (EPI == 2) v = 0.5f * v * (1.0f + erff(v * 0.70710678118654752f));
        const size_t idx = (size_t)row * N + col;
        if (EPI == 1) ((float*)Cout)[idx] = v + res[idx];
        else ((unsigned short*)Cout)[idx] = f2bf(v);
      }
    }
  }
}

// ---------- flash attention (unchanged from round 10) -------------------------
__global__ __launch_bounds__(256, 4) void attn_kernel(
    const unsigned short* __restrict__ qkv, const unsigned short* __restrict__ vt,
    unsigned short* __restrict__ op0, unsigned short* __restrict__ op1,
    float* __restrict__ lpart) {
  __shared__ unsigned short Kl[2][4096];
  __shared__ unsigned short Vl[2][4096];
  const int tid = threadIdx.x;
  const int wid = tid >> 6, lane = tid & 63;
  const int l31 = lane & 31, hiq = lane >> 5;
  const int kvh = blockIdx.z & 1, b = blockIdx.z >> 1;
  const int g = blockIdx.y * 16 + blockIdx.x;
  const int h = (g & 7) * 2 + (g >> 7);
  const int q0 = ((g >> 3) & 15) * 128 + wid * 32;
  const int LD = 3072;
  const size_t base = (size_t)b * 2048 * LD;
  const size_t kvoff = (size_t)kvh * 1024 * LD;

  short8 qb[4];
  {
    const unsigned short* qp = qkv + base + (size_t)(q0 + l31) * LD + h * 64 + hiq * 8;
#pragma unroll
    for (int ds = 0; ds < 4; ++ds) qb[ds] = *(const short8*)(qp + ds * 16);
  }

  f32x16 o0 = (f32x16)0.0f, o1 = (f32x16)0.0f;
  float la = 0.0f, lb = 0.0f;

  const int rw = lane >> 3;
  const int sgG = (lane & 7) ^ rw;
  const unsigned short* kdma = qkv + base + kvoff + 1024 + h * 64 + sgG * 8 +
                               (size_t)(wid * 16 + rw) * LD;
  const unsigned short* vdma = vt + (size_t)(b * 16 + h) * 64 * 2048 +
                               (size_t)(wid * 16 + rw) * 2048 + kvh * 1024 + sgG * 8;

  auto kstage = [&](int buf, int t) {
    GLD_LDS16(kdma + (size_t)t * 64 * LD, &Kl[buf][wid * 1024]);
    GLD_LDS16(kdma + (size_t)(t * 64 + 8) * LD, &Kl[buf][wid * 1024 + 512]);
  };
  auto vstage = [&](int buf, int t) {
    GLD_LDS16(vdma + t * 64, &Vl[buf][wid * 1024]);
    GLD_LDS16(vdma + 8 * 2048 + t * 64, &Vl[buf][wid * 1024 + 512]);
  };

  auto compute = [&](int ib) {
    const unsigned short* kl = Kl[ib];
    const unsigned short* vl = Vl[ib];
    short8 kf[2][4];
#pragma unroll
    for (int kvb = 0; kvb < 2; ++kvb)
#pragma unroll
      for (int ds = 0; ds < 4; ++ds)
        kf[kvb][ds] = *(const short8*)(
            kl + (kvb * 32 + l31) * 64 + (((2 * ds + hiq) ^ (l31 & 7)) * 8));

    f32x16 sA = (f32x16)0.0f, sB = (f32x16)0.0f;
    __builtin_amdgcn_s_setprio(1);
#pragma unroll
    for (int ds = 0; ds < 4; ++ds) {
      sA = MFMA32_BF16(kf[0][ds], qb[ds], sA);
      sB = MFMA32_BF16(kf[1][ds], qb[ds], sB);
    }
    __builtin_amdgcn_s_setprio(0);

#pragma unroll
    for (int kvb = 0; kvb < 2; ++kvb) {
      const f32x16 s = kvb ? sB : sA;
      unsigned P[8];
#pragma unroll
      for (int i = 0; i < 8; ++i) {
        const float pe = __expf(s[2 * i] * 0.125f);
        const float po = __expf(s[2 * i + 1] * 0.125f);
        la += pe; lb += po;
        P[i] = cvt_pk_bf16(pe, po);
      }
      PSWAP(P[0], P[2]); PSWAP(P[1], P[3]);
      PSWAP(P[4], P[6]); PSWAP(P[5], P[7]);
      const short8 pa0 = __builtin_bit_cast(short8, (u32x4){P[0], P[1], P[2], P[3]});
      const short8 pa1 = __builtin_bit_cast(short8, (u32x4){P[4], P[5], P[6], P[7]});
      const int sg0 = 4 * kvb + hiq, sg1 = 4 * kvb + 2 + hiq;
      const short8 v00 = *(const short8*)(vl + l31 * 64 + ((sg0 ^ (l31 & 7)) * 8));
      const short8 v01 = *(const short8*)(vl + l31 * 64 + ((sg1 ^ (l31 & 7)) * 8));
      const short8 v10 = *(const short8*)(vl + (32 + l31) * 64 + ((sg0 ^ (l31 & 7)) * 8));
      const short8 v11 = *(const short8*)(vl + (32 + l31) * 64 + ((sg1 ^ (l31 & 7)) * 8));
      __builtin_amdgcn_s_setprio(1);
      o0 = MFMA32_BF16(pa0, v00, o0);
      o0 = MFMA32_BF16(pa1, v01, o0);
      o1 = MFMA32_BF16(pa0, v10, o1);
      o1 = MFMA32_BF16(pa1, v11, o1);
      __builtin_amdgcn_s_setprio(0);
    }
  };

  kstage(0, 0);
  vstage(0, 0);
  for (int t = 0; t < 16; ++t) {
    waitcnt_vm<0>();
    __builtin_amdgcn_s_barrier();
    if (t < 15) { kstage((t + 1) & 1, t + 1); vstage((t + 1) & 1, t + 1); }
    compute(t & 1);
  }

  const float lsum = la + lb;
  const float lt = lsum + __shfl_xor(lsum, 32, 64);
  if (hiq == 0)
    lpart[(size_t)kvh * 65536 + ((size_t)(b * 2048 + q0 + l31) * 16) + h] = lt;

  unsigned short* op = kvh ? op1 : op0;
#pragma unroll
  for (int r = 0; r < 16; ++r) {
    const int crow = (r & 3) + 8 * (r >> 2) + 4 * hiq;
    const size_t rowb = (size_t)(b * 2048 + q0 + crow) * 1024 + h * 64 + l31;
    op[rowb]      = f2bf(o0[r]);
    op[rowb + 32] = f2bf(o1[r]);
  }
}

// ---------- combine KV-split halves: out = (O0 + O1) / (l0 + l1) ----------
__global__ __launch_bounds__(256) void attn_combine(
    const unsigned short* __restrict__ op0, unsigned short* __restrict__ op1io,
    const float* __restrict__ lpart) {
  const size_t i8 = (size_t)blockIdx.x * 256 + threadIdx.x;
  const size_t g = (i8 * 8) >> 6;
  const float inv = 1.0f / (lpart[g] + lpart[g + 65536]);
  const short8 a = *(const short8*)(op0 + i8 * 8);
  const short8 c = *(const short8*)(op1io + i8 * 8);
  short8 o;
#pragma unroll
  for (int j = 0; j < 8; ++j)
    o[j] = (short)f2bf((bf2f((unsigned short)a[j]) + bf2f((unsigned short)c[j])) * inv);
  *(short8*)(op1io + i8 * 8) = o;
}

// ---------- launcher ----------
extern "C" void kernel_launch(void* const* d_in, const int* in_sizes, int n_in,
                              void* d_out, int out_size, void* d_ws, size_t ws_size,
                              hipStream_t stream) {
  const float* x     = (const float*)d_in[0];
  const float* ln1_g = (const float*)d_in[1];
  const float* ln1_b = (const float*)d_in[2];
  const float* ln2_g = (const float*)d_in[3];
  const float* ln2_b = (const float*)d_in[4];
  const float* wq    = (const float*)d_in[5];
  const float* bq    = (const float*)d_in[6];
  const float* wk    = (const float*)d_in[7];
  const float* bk    = (const float*)d_in[8];
  const float* wv    = (const float*)d_in[9];
  const float* bv    = (const float*)d_in[10];
  const float* wo    = (const float*)d_in[11];
  const float* bo    = (const float*)d_in[12];
  const float* w1    = (const float*)d_in[13];
  const float* b1    = (const float*)d_in[14];
  const float* w2    = (const float*)d_in[15];
  const float* b2    = (const float*)d_in[16];
  float* out = (float*)d_out;

  // allow 128KB dynamic LDS for the 256^2 kernels (host-side, capture-safe)
  hipFuncSetAttribute((const void*)gemm256<0>,
                      hipFuncAttributeMaxDynamicSharedMemorySize, 131072);
  hipFuncSetAttribute((const void*)gemm256<2>,
                      hipFuncAttributeMaxDynamicSharedMemorySize, 131072);
  hipFuncSetAttribute((const void*)gemm256<3>,
                      hipFuncAttributeMaxDynamicSharedMemorySize, 131072);

  char* p = (char*)d_ws;
  unsigned short* ws_h     = (unsigned short*)p; p += 4096ull * 1024 * 2;
  unsigned short* ws_qkv   = (unsigned short*)p; p += 4096ull * 3072 * 2;
  unsigned short* ws_attn  = (unsigned short*)p; p += 4096ull * 1024 * 2;
  unsigned short* ws_wqkvT = (unsigned short*)p; p += 3072ull * 1024 * 2;
  unsigned short* ws_woT   = (unsigned short*)p; p += 1024ull * 1024 * 2;
  unsigned short* ws_w1T   = (unsigned short*)p; p += 4096ull * 1024 * 2;
  unsigned short* ws_w2T   = (unsigned short*)p; p += 1024ull * 4096 * 2;
  float*          ws_bqkv  = (float*)p;          p += 3072 * 4;
  float*          ws_l     = (float*)p;          p += 2ull * 65536 * 4;
  unsigned short* ws_ff = ws_qkv;   // FF [4096][4096] aliases qkv+attn (dead by then)
  unsigned short* ws_vt = ws_w1T;   // V^T 16MB aliases w1T/w2T (repacked AFTER attn)
  // FFN2 split-K bf16 partials [4096][1024] in dead regions at FFN2 time:
  unsigned short* ws_p0 = ws_h;                       // dead after FFN1
  unsigned short* ws_p1 = ws_attn;                    // dead after Wo
  unsigned short* ws_p2 = ws_wqkvT;                   // wqkvT+woT, dead after Wo
  unsigned short* ws_p3 = ws_w1T;                     // dead after FFN1

  const dim3 tb(32, 8);
  transpose_cast<<<dim3(2, 32, 16), tb, 0, stream>>>(
      wq, ws_wqkvT, 1024, 64, (size_t)(1024 * 64), (size_t)(64 * 1024));
  transpose_cast<<<dim3(2, 32, 16), tb, 0, stream>>>(
      wk, ws_wqkvT + 1024ull * 1024, 1024, 64, (size_t)(1024 * 64), (size_t)(64 * 1024));
  transpose_cast<<<dim3(2, 32, 16), tb, 0, stream>>>(
      wv, ws_wqkvT + 2048ull * 1024, 1024, 64, (size_t)(1024 * 64), (size_t)(64 * 1024));
  transpose_cast<<<dim3(32, 32, 1), tb, 0, stream>>>(wo, ws_woT, 1024, 1024, 0, 0);
  concat_bias<<<12, 256, 0, stream>>>(bq, bk, bv, ws_bqkv);

  // LN1 -> h
  ln_kernel<<<4096, 256, 0, stream>>>(x, ln1_g, ln1_b, ws_h);
  // QKV: [4096,1024] x [3072,1024]^T -> bf16 (256^2 8-phase)
  gemm256<0><<<dim3(12, 16, 1), 512, 131072, stream>>>(
      ws_h, ws_wqkvT, ws_bqkv, ws_qkv, 4096, 3072, 1024,
      nullptr, nullptr, nullptr, nullptr);
  // V^T: qkv V-cols -> vt[bh][64][2048]
  vtrans<<<dim3(32, 32), dim3(64, 8), 0, stream>>>(ws_qkv, ws_vt);
  // attention + combine
  attn_kernel<<<dim3(16, 16, 4), 256, 0, stream>>>(ws_qkv, ws_vt, ws_h, ws_attn, ws_l);
  attn_combine<<<2048, 256, 0, stream>>>(ws_h, ws_attn, ws_l);
  // FFN weight repacks (overwrite vt region; attn is done)
  transpose_cast<<<dim3(128, 32, 1), tb, 0, stream>>>(w1, ws_w1T, 1024, 4096, 0, 0);
  transpose_cast<<<dim3(32, 128, 1), tb, 0, stream>>>(w2, ws_w2T, 4096, 1024, 0, 0);
  // x1 = x + attn @ wo + bo  -> d_out (f32)
  gemm_bt<1, 64><<<dim3(16, 32), 256, 0, stream>>>(ws_attn, ws_woT, bo, x,
                                                   out, 4096, 1024, 1024);
  // LN2 -> h2 (rewrites ws_h fully)
  ln_kernel<<<4096, 256, 0, stream>>>(out, ln2_g, ln2_b, ws_h);
  // FFN1: gelu(h2 @ w1 + b1) -> bf16 (256^2 8-phase)
  gemm256<2><<<dim3(16, 16, 1), 512, 131072, stream>>>(
      ws_h, ws_w1T, b1, ws_ff, 4096, 4096, 1024,
      nullptr, nullptr, nullptr, nullptr);
  // FFN2: split-K=4 over 256^2 template -> bf16 partials (no bias)
  gemm256<3><<<dim3(4, 16, 4), 512, 131072, stream>>>(
      ws_ff, ws_w2T, nullptr, nullptr, 4096, 1024, 4096,
      ws_p0, ws_p1, ws_p2, ws_p3);
  // out = x1 + (P0+P1+P2+P3) + b2
  ffn2_combine<<<2048, 256, 0, stream>>>(ws_p0, ws_p1, ws_p2, ws_p3, b2, out);
}

// Round 12
// 239.067 us; speedup vs baseline: 1.0066x; 1.0066x over previous
//
#include <hip/hip_runtime.h>
#include <hip/hip_bf16.h>
#include <math.h>

// ---------- types / helpers ----------
typedef __attribute__((ext_vector_type(8))) short short8;    // 8 bf16
typedef __attribute__((ext_vector_type(4))) float f32x4;
typedef __attribute__((ext_vector_type(16))) float f32x16;
typedef __attribute__((ext_vector_type(4))) unsigned u32x4;

#define MFMA_BF16(a, b, c) __builtin_amdgcn_mfma_f32_16x16x32_bf16(a, b, c, 0, 0, 0)
#define MFMA32_BF16(a, b, c) __builtin_amdgcn_mfma_f32_32x32x16_bf16(a, b, c, 0, 0, 0)
#define BAR() __builtin_amdgcn_s_barrier()
#define SCHEDB() __builtin_amdgcn_sched_barrier(0)
// rule #18: lgkmcnt(0) + sched_barrier so MFMA can't hoist past the wait
#define LGKM0()                                             \
  do {                                                      \
    asm volatile("s_waitcnt lgkmcnt(0)" ::: "memory");      \
    __builtin_amdgcn_sched_barrier(0);                      \
  } while (0)

// async global->LDS, 16B per lane; LDS dest = wave-uniform base + lane*16
#define GLD_LDS16(g, l)                                              \
  __builtin_amdgcn_global_load_lds(                                  \
      (const __attribute__((address_space(1))) void*)(g),            \
      (__attribute__((address_space(3))) void*)(l), 16, 0, 0)

// counted vmcnt wait (T4): keep N VMEM ops in flight across the barrier
template <int N>
__device__ __forceinline__ void waitcnt_vm() {
  if constexpr (N == 0) asm volatile("s_waitcnt vmcnt(0)" ::: "memory");
  else if constexpr (N == 2) asm volatile("s_waitcnt vmcnt(2)" ::: "memory");
  else if constexpr (N == 4) asm volatile("s_waitcnt vmcnt(4)" ::: "memory");
  else if constexpr (N == 6) asm volatile("s_waitcnt vmcnt(6)" ::: "memory");
  else if constexpr (N == 8) asm volatile("s_waitcnt vmcnt(8)" ::: "memory");
}

// packed 2xf32 -> 2xbf16 (RNE); no builtin on gfx950 (m240) -> inline asm
__device__ __forceinline__ unsigned cvt_pk_bf16(float lo, float hi) {
  unsigned r;
  asm("v_cvt_pk_bf16_f32 %0, %1, %2" : "=v"(r) : "v"(lo), "v"(hi));
  return r;
}
#define PSWAP(a, b) asm volatile("v_permlane32_swap_b32 %0, %1" : "+v"(a), "+v"(b))

__device__ __forceinline__ unsigned short f2bf(float f) {
  union { float f; unsigned u; } v; v.f = f;
  unsigned r = v.u + 0x7FFFu + ((v.u >> 16) & 1u);   // RNE
  return (unsigned short)(r >> 16);
}
__device__ __forceinline__ float bf2f(unsigned short u) {
  union { unsigned u; float f; } v; v.u = ((unsigned)u) << 16;
  return v.f;
}

// ---------- weight repack: [R][C] f32 -> [C][R] bf16 (batched) ----------
__global__ __launch_bounds__(256) void transpose_cast(
    const float* __restrict__ in, unsigned short* __restrict__ out,
    int R, int C, size_t in_bs, size_t out_bs) {
  __shared__ float t[32][33];
  const float* inp = in + blockIdx.z * in_bs;
  unsigned short* outp = out + blockIdx.z * out_bs;
  const int c0 = blockIdx.x * 32, r0 = blockIdx.y * 32;
  const int tx = threadIdx.x, ty = threadIdx.y;
#pragma unroll
  for (int i = 0; i < 32; i += 8)
    t[ty + i][tx] = inp[(size_t)(r0 + ty + i) * C + c0 + tx];
  __syncthreads();
#pragma unroll
  for (int i = 0; i < 32; i += 8)
    outp[(size_t)(c0 + ty + i) * R + r0 + tx] = f2bf(t[tx][ty + i]);
}

__global__ void concat_bias(const float* __restrict__ bq, const float* __restrict__ bk,
                            const float* __restrict__ bv, float* __restrict__ bcat) {
  int i = blockIdx.x * 256 + threadIdx.x;
  if (i < 1024) bcat[i] = bq[i];
  else if (i < 2048) bcat[i] = bk[i - 1024];
  else if (i < 3072) bcat[i] = bv[i - 2048];
}

// ---------- V transpose: qkv V-cols [s][d] -> vt[b*16+h][d=64][s=2048] bf16 ----
__global__ __launch_bounds__(512) void vtrans(
    const unsigned short* __restrict__ qkv, unsigned short* __restrict__ vt) {
  __shared__ unsigned short t[64][65];
  const int bh = blockIdx.y;            // b*16+h
  const int s0 = blockIdx.x * 64;
  const int tx = threadIdx.x;           // 0..63 (d on read, s on write)
  const int ty = threadIdx.y;           // 0..7
  const unsigned short* in =
      qkv + (size_t)(bh >> 4) * 2048 * 3072 + 2048 + (bh & 15) * 64;
#pragma unroll
  for (int i = 0; i < 8; ++i)
    t[ty * 8 + i][tx] = in[(size_t)(s0 + ty * 8 + i) * 3072 + tx];
  __syncthreads();
  unsigned short* o = vt + (size_t)bh * 64 * 2048 + s0;
#pragma unroll
  for (int i = 0; i < 8; ++i)
    o[(size_t)(ty * 8 + i) * 2048 + tx] = t[tx][ty * 8 + i];
}

// ---------- LayerNorm: row of 1024 f32 -> bf16 ----------
__global__ __launch_bounds__(256) void ln_kernel(
    const float* __restrict__ x, const float* __restrict__ g,
    const float* __restrict__ bb, unsigned short* __restrict__ out) {
  const int row = blockIdx.x, tid = threadIdx.x;
  const float4 v = ((const float4*)(x + (size_t)row * 1024))[tid];
  float s = v.x + v.y + v.z + v.w;
  float ss = v.x * v.x + v.y * v.y + v.z * v.z + v.w * v.w;
#pragma unroll
  for (int k = 1; k < 64; k <<= 1) {
    s += __shfl_xor(s, k, 64);
    ss += __shfl_xor(ss, k, 64);
  }
  __shared__ float red[8];
  const int wid = tid >> 6;
  if ((tid & 63) == 0) { red[wid] = s; red[wid + 4] = ss; }
  __syncthreads();
  s = red[0] + red[1] + red[2] + red[3];
  ss = red[4] + red[5] + red[6] + red[7];
  const float mu = s * (1.0f / 1024.0f);
  const float var = ss * (1.0f / 1024.0f) - mu * mu;
  const float rs = rsqrtf(var + 1e-5f);
  const float4 gv = ((const float4*)g)[tid];
  const float4 bv = ((const float4*)bb)[tid];
  ushort4 o;
  o.x = f2bf((v.x - mu) * rs * gv.x + bv.x);
  o.y = f2bf((v.y - mu) * rs * gv.y + bv.y);
  o.z = f2bf((v.z - mu) * rs * gv.z + bv.z);
  o.w = f2bf((v.w - mu) * rs * gv.w + bv.w);
  ((ushort4*)(out + (size_t)row * 1024))[tid] = o;
}

// ---------- 256^2 8-phase GEMM, SINGLE barrier/phase: C = A[M,K] x Bt[N,K]^T --
// 512 thr = 8 waves (2M x 4N), per-wave out 128x64, BK=64, dbuf 128KB LDS.
// Phase = {BAR; ds-reads; stg; LGKM0; 16 MFMA}. 8 barriers/j-iter (was 16).
// Ledger (skew < 1 phase, barrier at each phase start):
//  - any stg target's last ds_read returned at the reader's LGKM0, which
//    precedes the barrier the stg follows -> no read/overwrite race;
//  - vmcnt(2) at p3/p7 tails (before next BAR) forces the whole next tile
//    landed while leaving the freshest A0 stage in flight (counted, T4).
// EPI 0: +bias->bf16 | 2: +bias+GELU->bf16 | 3: raw bf16 partial -> pz
template <int QM, int QN>
__device__ __forceinline__ void mfq(f32x4 (&acc)[8][4], short8 (&af)[4][2],
                                    short8 (&bf)[2][2]) {
  __builtin_amdgcn_s_setprio(1);
#pragma unroll
  for (int i = 0; i < 4; ++i)
#pragma unroll
    for (int nf = 0; nf < 2; ++nf) {
      acc[QM * 4 + i][QN * 2 + nf] =
          MFMA_BF16(af[i][0], bf[nf][0], acc[QM * 4 + i][QN * 2 + nf]);
      acc[QM * 4 + i][QN * 2 + nf] =
          MFMA_BF16(af[i][1], bf[nf][1], acc[QM * 4 + i][QN * 2 + nf]);
    }
  __builtin_amdgcn_s_setprio(0);
}

template <int EPI>
__global__ __launch_bounds__(512, 2) void gemm256(
    const unsigned short* __restrict__ A, const unsigned short* __restrict__ Bt,
    const float* __restrict__ bias, void* __restrict__ Cout,
    int M, int N, int K,
    unsigned short* __restrict__ p0p, unsigned short* __restrict__ p1p,
    unsigned short* __restrict__ p2p, unsigned short* __restrict__ p3p) {
  extern __shared__ unsigned short L[];   // [buf][op][half][8192] el = 128KB
  const int tid = threadIdx.x;
  const int wv = tid >> 6, lane = tid & 63;
  const int li = lane & 15, gi = lane >> 4;
  const int wm = wv >> 2, wn = wv & 3;    // 2 x 4 wave grid
  // T1: bijective XCD swizzle (nwg % 8 == 0 for all our grids)
  const int gx = gridDim.x;
  const int flat = blockIdx.y * gx + blockIdx.x;
  const int swz = (flat & 7) * ((gx * gridDim.y) >> 3) + (flat >> 3);
  const int bm = swz / gx, bn = swz - bm * gx;
  const size_t Ksz = (size_t)K;
  const int k0 = (int)(blockIdx.z << 10);   // 1024 K per z-slice, always

  auto lds = [&](int buf, int op, int half) -> unsigned short* {
    return L + (size_t)(((buf * 2 + op) * 2 + half)) * 8192;
  };

  // staging: issue covers rows (tid>>3) + c*64; seg pre-swizzled (both-sides, #21)
  const int sr8 = tid >> 3;
  const int segG = (tid & 7) ^ (sr8 & 7);
  const unsigned short* Ag = A + (size_t)(bm * 256 + sr8) * Ksz + segG * 8 + k0;
  const unsigned short* Bg = Bt + (size_t)(bn * 256 + sr8) * Ksz + segG * 8 + k0;
  const int wbase = wv * 512;

  auto stg = [&](int buf, int op, int half, int tile) {
    const unsigned short* g =
        (op ? Bg : Ag) + (size_t)(half * 128) * Ksz + (tile & 15) * 64;
    unsigned short* d = lds(buf, op, half);
    GLD_LDS16(g, d + wbase);
    GLD_LDS16(g + (size_t)64 * Ksz, d + 4096 + wbase);
  };

  f32x4 acc[8][4];
#pragma unroll
  for (int m = 0; m < 8; ++m)
#pragma unroll
    for (int n = 0; n < 4; ++n) acc[m][n] = (f32x4)0.0f;

  short8 af[4][2], b0[2][2], b1[2][2];
  auto ldA = [&](int buf, int qm) {
    const unsigned short* p = lds(buf, 0, wm);
#pragma unroll
    for (int i = 0; i < 4; ++i) {
      const int r = qm * 64 + i * 16 + li;
#pragma unroll
      for (int kk = 0; kk < 2; ++kk)
        af[i][kk] = *(const short8*)(p + r * 64 + (((kk * 4 + gi) ^ (r & 7)) * 8));
    }
  };
  auto ldB = [&](short8 (&bf)[2][2], int buf, int qn) {
    const unsigned short* p = lds(buf, 1, wn >> 1);
#pragma unroll
    for (int nf = 0; nf < 2; ++nf) {
      const int r = (wn & 1) * 64 + qn * 32 + nf * 16 + li;
#pragma unroll
      for (int kk = 0; kk < 2; ++kk)
        bf[nf][kk] = *(const short8*)(p + r * 64 + (((kk * 4 + gi) ^ (r & 7)) * 8));
    }
  };

  // prologue: T0 all halves + A0(T1); vmcnt(2) leaves A0(T1) in flight.
  // (each wave's vmcnt precedes its first barrier -> publish is ordered)
  stg(0, 0, 0, 0); stg(0, 0, 1, 0); stg(0, 1, 0, 0); stg(0, 1, 1, 0);
  stg(1, 0, 0, 1);
  waitcnt_vm<2>();

  for (int j = 0; j < 8; ++j) {
    const int t1 = 2 * j + 1, t2 = 2 * j + 2, t3 = 2 * j + 3;
    // p0 (buf0, q00)
    BAR();
    ldA(0, 0); ldB(b0, 0, 0);
    stg(1, 0, 1, t1); stg(1, 1, 0, t1);
    LGKM0();
    mfq<0, 0>(acc, af, b0);
    // p1 (q01)
    BAR();
    ldB(b1, 0, 1);
    stg(1, 1, 1, t1);
    LGKM0();
    mfq<0, 1>(acc, af, b1);
    // p2 (q10)
    BAR();
    ldA(0, 1);
    LGKM0();
    mfq<1, 0>(acc, af, b0);
    // p3 (q11): no reads; stage A0(t2); vmcnt(2) -> tile t1 landed before p4 BAR
    BAR();
    stg(0, 0, 0, t2);
    waitcnt_vm<2>();
    mfq<1, 1>(acc, af, b1);
    // p4 (buf1, q00)
    BAR();
    ldA(1, 0); ldB(b0, 1, 0);
    stg(0, 0, 1, t2); stg(0, 1, 0, t2);
    LGKM0();
    mfq<0, 0>(acc, af, b0);
    // p5 (q01)
    BAR();
    ldB(b1, 1, 1);
    stg(0, 1, 1, t2);
    LGKM0();
    mfq<0, 1>(acc, af, b1);
    // p6 (q10)
    BAR();
    ldA(1, 1);
    LGKM0();
    mfq<1, 0>(acc, af, b0);
    // p7 (q11): stage A0(t3); vmcnt(2) -> tile t2 landed before next p0 BAR
    BAR();
    stg(1, 0, 0, t3);
    waitcnt_vm<2>();
    mfq<1, 1>(acc, af, b1);
  }

  // epilogue: C row = gi*4+reg (16x16 layout), col = li
  unsigned short* Pz =
      (EPI == 3) ? ((blockIdx.z == 0) ? p0p : (blockIdx.z == 1) ? p1p
                    : (blockIdx.z == 2) ? p2p : p3p)
                 : (unsigned short*)Cout;
  const int row0 = bm * 256 + wm * 128 + gi * 4;
  const int col0 = bn * 256 + wn * 64 + li;
#pragma unroll
  for (int mf = 0; mf < 8; ++mf) {
#pragma unroll
    for (int nf = 0; nf < 4; ++nf) {
      const int col = col0 + nf * 16;
      const float bi = (EPI == 3) ? 0.0f : bias[col];
#pragma unroll
      for (int r = 0; r < 4; ++r) {
        const int row = row0 + mf * 16 + r;
        float v = acc[mf][nf][r] + bi;
        if (EPI == 2) v = 0.5f * v * (1.0f + erff(v * 0.70710678118654752f));
        Pz[(size_t)row * N + col] = f2bf(v);
      }
    }
  }
}

// ---------- FFN2 split-K combine: out += P0+P1+P2+P3 + b2 (out holds x1) ------
__global__ __launch_bounds__(256) void ffn2_combine(
    const unsigned short* __restrict__ p0, const unsigned short* __restrict__ p1,
    const unsigned short* __restrict__ p2, const unsigned short* __restrict__ p3,
    const float* __restrict__ b2, float* __restrict__ out) {
  const size_t i8 = (size_t)blockIdx.x * 256 + threadIdx.x;   // 8-elem group
  const size_t e0 = i8 * 8;
  const int col = (int)(e0 & 1023);
  const short8 a0 = *(const short8*)(p0 + e0);
  const short8 a1 = *(const short8*)(p1 + e0);
  const short8 a2 = *(const short8*)(p2 + e0);
  const short8 a3 = *(const short8*)(p3 + e0);
  float4 o0 = ((float4*)out)[i8 * 2];
  float4 o1 = ((float4*)out)[i8 * 2 + 1];
  float v[8];
#pragma unroll
  for (int j = 0; j < 8; ++j)
    v[j] = bf2f((unsigned short)a0[j]) + bf2f((unsigned short)a1[j]) +
           bf2f((unsigned short)a2[j]) + bf2f((unsigned short)a3[j]) + b2[col + j];
  o0.x += v[0]; o0.y += v[1]; o0.z += v[2]; o0.w += v[3];
  o1.x += v[4]; o1.y += v[5]; o1.z += v[6]; o1.w += v[7];
  ((float4*)out)[i8 * 2] = o0;
  ((float4*)out)[i8 * 2 + 1] = o1;
}

// ---------- 128xBN pipelined GEMM (counted vmcnt) for N=1024 ops --------------
// EPI 1: +bias +res(f32) -> f32
template <int EPI, int BN>
__global__ __launch_bounds__(256, (BN == 128) ? 2 : 3) void gemm_bt(
    const unsigned short* __restrict__ A, const unsigned short* __restrict__ Bt,
    const float* __restrict__ bias, const float* __restrict__ res,
    void* __restrict__ Cout, int M, int N, int K) {
  constexpr int NFR = BN / 32;
  constexpr int BISS = BN / 32;
  constexpr int ISS = 4 + BISS;
  __shared__ unsigned short As[2][128 * 64];
  __shared__ unsigned short Bs[2][BN * 64];
  const int tid = threadIdx.x;
  const int wid = tid >> 6, lane = tid & 63;
  const int li = lane & 15, gi = lane >> 4;
  const int bm = blockIdx.y, bn = blockIdx.x;
  const int wr = (wid >> 1) << 6;
  const int wc = (wid & 1) * (BN / 2);

  f32x4 acc[4][NFR];
#pragma unroll
  for (int m = 0; m < 4; ++m)
#pragma unroll
    for (int n = 0; n < NFR; ++n) acc[m][n] = (f32x4)0.0f;

  const size_t Ksz = (size_t)K;
  const int srow = tid >> 3;
  const int segG = (tid & 7) ^ (srow & 7);
  const unsigned short* Ab = A + (size_t)(bm * 128 + srow) * Ksz + segG * 8;
  const unsigned short* Bb = Bt + (size_t)(bn * BN + srow) * Ksz + segG * 8;

  auto stage = [&](int buf, int kt) {
#pragma unroll
    for (int c = 0; c < 4; ++c)
      GLD_LDS16(Ab + (size_t)(c * 32) * Ksz + kt, &As[buf][c * 2048 + wid * 512]);
#pragma unroll
    for (int c = 0; c < BISS; ++c)
      GLD_LDS16(Bb + (size_t)(c * 32) * Ksz + kt, &Bs[buf][c * 2048 + wid * 512]);
  };

  auto compute = [&](int ib) {
    const unsigned short* As_ = As[ib];
    const unsigned short* Bs_ = Bs[ib];
    short8 af[4][2], bf[NFR][2];
#pragma unroll
    for (int m = 0; m < 4; ++m)
#pragma unroll
      for (int kk = 0; kk < 2; ++kk) {
        const int row = wr + m * 16 + li;
        af[m][kk] = *(const short8*)(As_ + row * 64 + ((kk * 4 + gi) ^ (row & 7)) * 8);
      }
#pragma unroll
    for (int n = 0; n < NFR; ++n)
#pragma unroll
      for (int kk = 0; kk < 2; ++kk) {
        const int row = wc + n * 16 + li;
        bf[n][kk] = *(const short8*)(Bs_ + row * 64 + ((kk * 4 + gi) ^ (row & 7)) * 8);
      }
    __builtin_amdgcn_s_setprio(1);
#pragma unroll
    for (int m = 0; m < 4; ++m)
#pragma unroll
      for (int n = 0; n < NFR; ++n) {
        acc[m][n] = MFMA_BF16(af[m][0], bf[n][0], acc[m][n]);
        acc[m][n] = MFMA_BF16(af[m][1], bf[n][1], acc[m][n]);
      }
    __builtin_amdgcn_s_setprio(0);
  };

  const int KT = K >> 6;
  stage(0, 0);
  for (int i = 0; i < KT - 1; ++i) {
    stage((i + 1) & 1, (i + 1) << 6);
    waitcnt_vm<ISS>();
    __builtin_amdgcn_s_barrier();
    __builtin_amdgcn_sched_barrier(0);
    compute(i & 1);
    __builtin_amdgcn_s_barrier();
  }
  waitcnt_vm<0>();
  __builtin_amdgcn_s_barrier();
  __builtin_amdgcn_sched_barrier(0);
  compute((KT - 1) & 1);

  const int row_base = bm * 128 + wr + gi * 4;
  const int col_base = bn * BN + wc + li;
#pragma unroll
  for (int m = 0; m < 4; ++m) {
#pragma unroll
    for (int n = 0; n < NFR; ++n) {
      const int col = col_base + n * 16;
      const float bi = bias[col];
#pragma unroll
      for (int r = 0; r < 4; ++r) {
        const int row = row_base + m * 16 + r;
        float v = acc[m][n][r] + bi;
        if (EPI == 2) v = 0.5f * v * (1.0f + erff(v * 0.70710678118654752f));
        const size_t idx = (size_t)row * N + col;
        if (EPI == 1) ((float*)Cout)[idx] = v + res[idx];
        else ((unsigned short*)Cout)[idx] = f2bf(v);
      }
    }
  }
}

// ---------- flash attention (unchanged) ---------------------------------------
__global__ __launch_bounds__(256, 4) void attn_kernel(
    const unsigned short* __restrict__ qkv, const unsigned short* __restrict__ vt,
    unsigned short* __restrict__ op0, unsigned short* __restrict__ op1,
    float* __restrict__ lpart) {
  __shared__ unsigned short Kl[2][4096];
  __shared__ unsigned short Vl[2][4096];
  const int tid = threadIdx.x;
  const int wid = tid >> 6, lane = tid & 63;
  const int l31 = lane & 31, hiq = lane >> 5;
  const int kvh = blockIdx.z & 1, b = blockIdx.z >> 1;
  const int g = blockIdx.y * 16 + blockIdx.x;
  const int h = (g & 7) * 2 + (g >> 7);
  const int q0 = ((g >> 3) & 15) * 128 + wid * 32;
  const int LD = 3072;
  const size_t base = (size_t)b * 2048 * LD;
  const size_t kvoff = (size_t)kvh * 1024 * LD;

  short8 qb[4];
  {
    const unsigned short* qp = qkv + base + (size_t)(q0 + l31) * LD + h * 64 + hiq * 8;
#pragma unroll
    for (int ds = 0; ds < 4; ++ds) qb[ds] = *(const short8*)(qp + ds * 16);
  }

  f32x16 o0 = (f32x16)0.0f, o1 = (f32x16)0.0f;
  float la = 0.0f, lb = 0.0f;

  const int rw = lane >> 3;
  const int sgG = (lane & 7) ^ rw;
  const unsigned short* kdma = qkv + base + kvoff + 1024 + h * 64 + sgG * 8 +
                               (size_t)(wid * 16 + rw) * LD;
  const unsigned short* vdma = vt + (size_t)(b * 16 + h) * 64 * 2048 +
                               (size_t)(wid * 16 + rw) * 2048 + kvh * 1024 + sgG * 8;

  auto kstage = [&](int buf, int t) {
    GLD_LDS16(kdma + (size_t)t * 64 * LD, &Kl[buf][wid * 1024]);
    GLD_LDS16(kdma + (size_t)(t * 64 + 8) * LD, &Kl[buf][wid * 1024 + 512]);
  };
  auto vstage = [&](int buf, int t) {
    GLD_LDS16(vdma + t * 64, &Vl[buf][wid * 1024]);
    GLD_LDS16(vdma + 8 * 2048 + t * 64, &Vl[buf][wid * 1024 + 512]);
  };

  auto compute = [&](int ib) {
    const unsigned short* kl = Kl[ib];
    const unsigned short* vl = Vl[ib];
    short8 kf[2][4];
#pragma unroll
    for (int kvb = 0; kvb < 2; ++kvb)
#pragma unroll
      for (int ds = 0; ds < 4; ++ds)
        kf[kvb][ds] = *(const short8*)(
            kl + (kvb * 32 + l31) * 64 + (((2 * ds + hiq) ^ (l31 & 7)) * 8));

    f32x16 sA = (f32x16)0.0f, sB = (f32x16)0.0f;
    __builtin_amdgcn_s_setprio(1);
#pragma unroll
    for (int ds = 0; ds < 4; ++ds) {
      sA = MFMA32_BF16(kf[0][ds], qb[ds], sA);
      sB = MFMA32_BF16(kf[1][ds], qb[ds], sB);
    }
    __builtin_amdgcn_s_setprio(0);

#pragma unroll
    for (int kvb = 0; kvb < 2; ++kvb) {
      const f32x16 s = kvb ? sB : sA;
      unsigned P[8];
#pragma unroll
      for (int i = 0; i < 8; ++i) {
        const float pe = __expf(s[2 * i] * 0.125f);
        const float po = __expf(s[2 * i + 1] * 0.125f);
        la += pe; lb += po;
        P[i] = cvt_pk_bf16(pe, po);
      }
      PSWAP(P[0], P[2]); PSWAP(P[1], P[3]);
      PSWAP(P[4], P[6]); PSWAP(P[5], P[7]);
      const short8 pa0 = __builtin_bit_cast(short8, (u32x4){P[0], P[1], P[2], P[3]});
      const short8 pa1 = __builtin_bit_cast(short8, (u32x4){P[4], P[5], P[6], P[7]});
      const int sg0 = 4 * kvb + hiq, sg1 = 4 * kvb + 2 + hiq;
      const short8 v00 = *(const short8*)(vl + l31 * 64 + ((sg0 ^ (l31 & 7)) * 8));
      const short8 v01 = *(const short8*)(vl + l31 * 64 + ((sg1 ^ (l31 & 7)) * 8));
      const short8 v10 = *(const short8*)(vl + (32 + l31) * 64 + ((sg0 ^ (l31 & 7)) * 8));
      const short8 v11 = *(const short8*)(vl + (32 + l31) * 64 + ((sg1 ^ (l31 & 7)) * 8));
      __builtin_amdgcn_s_setprio(1);
      o0 = MFMA32_BF16(pa0, v00, o0);
      o0 = MFMA32_BF16(pa1, v01, o0);
      o1 = MFMA32_BF16(pa0, v10, o1);
      o1 = MFMA32_BF16(pa1, v11, o1);
      __builtin_amdgcn_s_setprio(0);
    }
  };

  kstage(0, 0);
  vstage(0, 0);
  for (int t = 0; t < 16; ++t) {
    waitcnt_vm<0>();
    __builtin_amdgcn_s_barrier();
    if (t < 15) { kstage((t + 1) & 1, t + 1); vstage((t + 1) & 1, t + 1); }
    compute(t & 1);
  }

  const float lsum = la + lb;
  const float lt = lsum + __shfl_xor(lsum, 32, 64);
  if (hiq == 0)
    lpart[(size_t)kvh * 65536 + ((size_t)(b * 2048 + q0 + l31) * 16) + h] = lt;

  unsigned short* op = kvh ? op1 : op0;
#pragma unroll
  for (int r = 0; r < 16; ++r) {
    const int crow = (r & 3) + 8 * (r >> 2) + 4 * hiq;
    const size_t rowb = (size_t)(b * 2048 + q0 + crow) * 1024 + h * 64 + l31;
    op[rowb]      = f2bf(o0[r]);
    op[rowb + 32] = f2bf(o1[r]);
  }
}

// ---------- combine KV-split halves: out = (O0 + O1) / (l0 + l1) ----------
__global__ __launch_bounds__(256) void attn_combine(
    const unsigned short* __restrict__ op0, unsigned short* __restrict__ op1io,
    const float* __restrict__ lpart) {
  const size_t i8 = (size_t)blockIdx.x * 256 + threadIdx.x;
  const size_t g = (i8 * 8) >> 6;
  const float inv = 1.0f / (lpart[g] + lpart[g + 65536]);
  const short8 a = *(const short8*)(op0 + i8 * 8);
  const short8 c = *(const short8*)(op1io + i8 * 8);
  short8 o;
#pragma unroll
  for (int j = 0; j < 8; ++j)
    o[j] = (short)f2bf((bf2f((unsigned short)a[j]) + bf2f((unsigned short)c[j])) * inv);
  *(short8*)(op1io + i8 * 8) = o;
}

// ---------- launcher ----------
extern "C" void kernel_launch(void* const* d_in, const int* in_sizes, int n_in,
                              void* d_out, int out_size, void* d_ws, size_t ws_size,
                              hipStream_t stream) {
  const float* x     = (const float*)d_in[0];
  const float* ln1_g = (const float*)d_in[1];
  const float* ln1_b = (const float*)d_in[2];
  const float* ln2_g = (const float*)d_in[3];
  const float* ln2_b = (const float*)d_in[4];
  const float* wq    = (const float*)d_in[5];
  const float* bq    = (const float*)d_in[6];
  const float* wk    = (const float*)d_in[7];
  const float* bk    = (const float*)d_in[8];
  const float* wv    = (const float*)d_in[9];
  const float* bv    = (const float*)d_in[10];
  const float* wo    = (const float*)d_in[11];
  const float* bo    = (const float*)d_in[12];
  const float* w1    = (const float*)d_in[13];
  const float* b1    = (const float*)d_in[14];
  const float* w2    = (const float*)d_in[15];
  const float* b2    = (const float*)d_in[16];
  float* out = (float*)d_out;

  // allow 128KB dynamic LDS for the 256^2 kernels (host-side, capture-safe)
  hipFuncSetAttribute((const void*)gemm256<0>,
                      hipFuncAttributeMaxDynamicSharedMemorySize, 131072);
  hipFuncSetAttribute((const void*)gemm256<2>,
                      hipFuncAttributeMaxDynamicSharedMemorySize, 131072);
  hipFuncSetAttribute((const void*)gemm256<3>,
                      hipFuncAttributeMaxDynamicSharedMemorySize, 131072);

  char* p = (char*)d_ws;
  unsigned short* ws_h     = (unsigned short*)p; p += 4096ull * 1024 * 2;
  unsigned short* ws_qkv   = (unsigned short*)p; p += 4096ull * 3072 * 2;
  unsigned short* ws_attn  = (unsigned short*)p; p += 4096ull * 1024 * 2;
  unsigned short* ws_wqkvT = (unsigned short*)p; p += 3072ull * 1024 * 2;
  unsigned short* ws_woT   = (unsigned short*)p; p += 1024ull * 1024 * 2;
  unsigned short* ws_w1T   = (unsigned short*)p; p += 4096ull * 1024 * 2;
  unsigned short* ws_w2T   = (unsigned short*)p; p += 1024ull * 4096 * 2;
  float*          ws_bqkv  = (float*)p;          p += 3072 * 4;
  float*          ws_l     = (float*)p;          p += 2ull * 65536 * 4;
  unsigned short* ws_ff = ws_qkv;   // FF [4096][4096] aliases qkv+attn (dead by then)
  unsigned short* ws_vt = ws_w1T;   // V^T 16MB aliases w1T/w2T (repacked AFTER attn)
  // FFN2 split-K bf16 partials [4096][1024] in dead regions at FFN2 time:
  unsigned short* ws_p0 = ws_h;                       // dead after FFN1
  unsigned short* ws_p1 = ws_attn;                    // dead after Wo
  unsigned short* ws_p2 = ws_wqkvT;                   // wqkvT+woT, dead after Wo
  unsigned short* ws_p3 = ws_w1T;                     // dead after FFN1

  const dim3 tb(32, 8);
  transpose_cast<<<dim3(2, 32, 16), tb, 0, stream>>>(
      wq, ws_wqkvT, 1024, 64, (size_t)(1024 * 64), (size_t)(64 * 1024));
  transpose_cast<<<dim3(2, 32, 16), tb, 0, stream>>>(
      wk, ws_wqkvT + 1024ull * 1024, 1024, 64, (size_t)(1024 * 64), (size_t)(64 * 1024));
  transpose_cast<<<dim3(2, 32, 16), tb, 0, stream>>>(
      wv, ws_wqkvT + 2048ull * 1024, 1024, 64, (size_t)(1024 * 64), (size_t)(64 * 1024));
  transpose_cast<<<dim3(32, 32, 1), tb, 0, stream>>>(wo, ws_woT, 1024, 1024, 0, 0);
  concat_bias<<<12, 256, 0, stream>>>(bq, bk, bv, ws_bqkv);

  // LN1 -> h
  ln_kernel<<<4096, 256, 0, stream>>>(x, ln1_g, ln1_b, ws_h);
  // QKV: [4096,1024] x [3072,1024]^T -> bf16 (256^2 8-phase)
  gemm256<0><<<dim3(12, 16, 1), 512, 131072, stream>>>(
      ws_h, ws_wqkvT, ws_bqkv, ws_qkv, 4096, 3072, 1024,
      nullptr, nullptr, nullptr, nullptr);
  // V^T: qkv V-cols -> vt[bh][64][2048]
  vtrans<<<dim3(32, 32), dim3(64, 8), 0, stream>>>(ws_qkv, ws_vt);
  // attention + combine
  attn_kernel<<<dim3(16, 16, 4), 256, 0, stream>>>(ws_qkv, ws_vt, ws_h, ws_attn, ws_l);
  attn_combine<<<2048, 256, 0, stream>>>(ws_h, ws_attn, ws_l);
  // FFN weight repacks (overwrite vt region; attn is done)
  transpose_cast<<<dim3(128, 32, 1), tb, 0, stream>>>(w1, ws_w1T, 1024, 4096, 0, 0);
  transpose_cast<<<dim3(32, 128, 1), tb, 0, stream>>>(w2, ws_w2T, 4096, 1024, 0, 0);
  // x1 = x + attn @ wo + bo  -> d_out (f32)
  gemm_bt<1, 64><<<dim3(16, 32), 256, 0, stream>>>(ws_attn, ws_woT, bo, x,
                                                   out, 4096, 1024, 1024);
  // LN2 -> h2 (rewrites ws_h fully)
  ln_kernel<<<4096, 256, 0, stream>>>(out, ln2_g, ln2_b, ws_h);
  // FFN1: gelu(h2 @ w1 + b1) -> bf16 (256^2 8-phase)
  gemm256<2><<<dim3(16, 16, 1), 512, 131072, stream>>>(
      ws_h, ws_w1T, b1, ws_ff, 4096, 4096, 1024,
      nullptr, nullptr, nullptr, nullptr);
  // FFN2: split-K=4 over 256^2 template -> bf16 partials (no bias)
  gemm256<3><<<dim3(4, 16, 4), 512, 131072, stream>>>(
      ws_ff, ws_w2T, nullptr, nullptr, 4096, 1024, 4096,
      ws_p0, ws_p1, ws_p2, ws_p3);
  // out = x1 + (P0+P1+P2+P3) + b2
  ffn2_combine<<<2048, 256, 0, stream>>>(ws_p0, ws_p1, ws_p2, ws_p3, b2, out);
}